// Round 3
// baseline (30.150 us; speedup 1.0000x reference)
//
#include <hip/hip_runtime.h>
#include <math.h>

// Dims fixed by reference setup_inputs():
//   x   : (NS=1024, NN=192) f32 in {-1,+1}
//   W2  : (DD=24)           f32
//   W3  : (DD, DD)          f32
//   phi : (NN, 2)           f32
//   nd  : (NN, NN)          i32 in [0, DD), SYMMETRIC
// out  : (NS,) f32 = J2 + J3 + logmf
//
// c[j,r] = sum_i x_i [nd[j,i]==r] = 2*popc(M[j][r] & P[n]) - popc(M[j][r])
// out[n] = sum_j x_j*(0.5*<c_j,W2> + c_j^T W3 c_j) + sum_j log(phi[j, x_j>0])
// Quadratic form via symmetrized triangular Q: q = sum_r c_r * sum_{s>=r} Q[r][s] c_s

#define NS 1024
#define NN 192
#define DD 24

typedef unsigned long long ull;

// ws layout (uints): Mbuf [NN][DD][8] (words 0..5 = mask, 6 = -(float)cnt, 7 pad),
// then Pd [6][NS], then Qbuf [DD*DD] floats.
#define M_WORDS (NN * DD * 8)
#define P_WORDS (6 * NS)

// Blocks 0..NN-1      : masks + counts for row j (nd symmetric -> row == col).
// Blocks NN..NN+NS-1  : pack x-sign bits for sample n; out[n] = logmf[n].
// Block  NN+NS        : symmetrized triangular Q from W3.
__global__ __launch_bounds__(192) void prep_kernel(
    const float* __restrict__ x,
    const float* __restrict__ W3,
    const float* __restrict__ phi,
    const int*   __restrict__ nd,
    unsigned* __restrict__ Mbuf,
    unsigned* __restrict__ Pd,
    float* __restrict__ Qbuf,
    float* __restrict__ out)
{
    const int tid = threadIdx.x;   // 0..191
    const int wv  = tid >> 6;      // wave 0..2
    const int b   = blockIdx.x;

    if (b < NN) {
        const int j   = b;
        const int ndv = nd[j * NN + tid];   // coalesced row read
        __shared__ unsigned smask[DD][6];
        #pragma unroll
        for (int r = 0; r < DD; ++r) {
            ull m = __ballot(ndv == r);
            if ((tid & 63) == 0) {
                smask[r][2 * wv]     = (unsigned)m;
                smask[r][2 * wv + 1] = (unsigned)(m >> 32);
            }
        }
        __syncthreads();
        // 192 threads write the 24*8 output words for this j
        const int r = tid >> 3, w = tid & 7;
        unsigned v;
        if (w < 6) {
            v = smask[r][w];
        } else if (w == 6) {
            int cnt = __popc(smask[r][0]) + __popc(smask[r][1]) + __popc(smask[r][2])
                    + __popc(smask[r][3]) + __popc(smask[r][4]) + __popc(smask[r][5]);
            v = __float_as_uint(-(float)cnt);
        } else {
            v = 0u;
        }
        Mbuf[(j * DD + r) * 8 + w] = v;
    } else if (b < NN + NS) {
        const int n    = b - NN;
        const float xv = x[n * NN + tid];
        const int bit  = (xv > 0.0f) ? 1 : 0;
        ull m = __ballot(bit);
        if ((tid & 63) == 0) {
            Pd[(2 * wv    ) * NS + n] = (unsigned)m;
            Pd[(2 * wv + 1) * NS + n] = (unsigned)(m >> 32);
        }
        float contrib = logf(phi[tid * 2 + bit]);
        __shared__ float red[3];
        #pragma unroll
        for (int off = 32; off >= 1; off >>= 1)
            contrib += __shfl_down(contrib, off, 64);
        if ((tid & 63) == 0) red[wv] = contrib;
        __syncthreads();
        if (tid == 0) out[n] = red[0] + red[1] + red[2];
    } else {
        for (int t = tid; t < DD * DD; t += 192) {
            const int r = t / DD, s = t % DD;
            float q = 0.0f;
            if (s > r)       q = W3[r * DD + s] + W3[s * DD + r];
            else if (s == r) q = W3[r * DD + r];
            Qbuf[t] = q;
        }
    }
}

// Grid (NS/64, NN/8), block 512 = 8 waves. Wave wv handles j = blockIdx.y*8+wv,
// lanes = 64 consecutive samples. Per-block LDS reduce -> 1 atomic per (block,n).
__global__ __launch_bounds__(512) void main_kernel(
    const float* __restrict__ W2,
    const float* __restrict__ Qbuf,
    const unsigned* __restrict__ Mbuf,
    const unsigned* __restrict__ Pd,
    float* __restrict__ out)
{
    const int lane = threadIdx.x & 63;
    const int wv   = threadIdx.x >> 6;
    const int n    = blockIdx.x * 64 + lane;
    int j = blockIdx.y * 8 + wv;
    j = __builtin_amdgcn_readfirstlane(j);

    const unsigned p0 = Pd[0 * NS + n];
    const unsigned p1 = Pd[1 * NS + n];
    const unsigned p2 = Pd[2 * NS + n];
    const unsigned p3 = Pd[3 * NS + n];
    const unsigned p4 = Pd[4 * NS + n];
    const unsigned p5 = Pd[5 * NS + n];

    const unsigned* __restrict__ Mj = &Mbuf[j * DD * 8];

    float c[DD];
    #pragma unroll
    for (int r = 0; r < DD; ++r) {
        const unsigned m0 = Mj[r * 8 + 0];
        const unsigned m1 = Mj[r * 8 + 1];
        const unsigned m2 = Mj[r * 8 + 2];
        const unsigned m3 = Mj[r * 8 + 3];
        const unsigned m4 = Mj[r * 8 + 4];
        const unsigned m5 = Mj[r * 8 + 5];
        const float ncnt  = __uint_as_float(Mj[r * 8 + 6]);  // -(float)popc(M)
        int pc = __popc(m0 & p0) + __popc(m1 & p1) + __popc(m2 & p2)
               + __popc(m3 & p3) + __popc(m4 & p4) + __popc(m5 & p5);
        c[r] = fmaf(2.0f, (float)pc, ncnt);
    }

    // triangular quadratic form + W2 dot
    float q = 0.0f, l2 = 0.0f;
    #pragma unroll
    for (int r = 0; r < DD; ++r) {
        float t = Qbuf[r * DD + r] * c[r];
        #pragma unroll
        for (int s = r + 1; s < DD; ++s) t = fmaf(Qbuf[r * DD + s], c[s], t);
        q  = fmaf(c[r], t, q);
        l2 = fmaf(W2[r], c[r], l2);
    }

    // x[n,j] sign = bit j of P (j uniform -> cheap select)
    const int w = j >> 5, bpos = j & 31;
    unsigned pw = (w == 0) ? p0 : (w == 1) ? p1 : (w == 2) ? p2
                : (w == 3) ? p3 : (w == 4) ? p4 : p5;
    const float xj = ((pw >> bpos) & 1u) ? 1.0f : -1.0f;

    const float acc = xj * fmaf(0.5f, l2, q);

    __shared__ float part[8][64];
    part[wv][lane] = acc;
    __syncthreads();
    if (wv == 0) {
        float s = part[0][lane] + part[1][lane] + part[2][lane] + part[3][lane]
                + part[4][lane] + part[5][lane] + part[6][lane] + part[7][lane];
        unsafeAtomicAdd(&out[n], s);   // 24 blocks per n
    }
}

extern "C" void kernel_launch(void* const* d_in, const int* in_sizes, int n_in,
                              void* d_out, int out_size, void* d_ws, size_t ws_size,
                              hipStream_t stream) {
    const float* x   = (const float*)d_in[0];
    const float* W2  = (const float*)d_in[1];
    const float* W3  = (const float*)d_in[2];
    const float* phi = (const float*)d_in[3];
    const int*   nd  = (const int*)d_in[4];
    float* out = (float*)d_out;

    unsigned* Mbuf = (unsigned*)d_ws;
    unsigned* Pd   = Mbuf + M_WORDS;
    float*    Qbuf = (float*)(Pd + P_WORDS);

    prep_kernel<<<NN + NS + 1, 192, 0, stream>>>(x, W3, phi, nd, Mbuf, Pd, Qbuf, out);
    main_kernel<<<dim3(NS / 64, NN / 8), 512, 0, stream>>>(W2, Qbuf, Mbuf, Pd, out);
}